// Round 4
// baseline (216.251 us; speedup 1.0000x reference)
//
#include <hip/hip_runtime.h>
#include <stdint.h>

#define NTOK 197
#define HD 64
#define NH 12
#define CDIM 768
#define BB 64
#define MTOT (BB*NTOK)      /* 12608 */
#define MPAD 12672          /* 99*128 */
#define SCALE 0.125f

typedef __attribute__((ext_vector_type(8))) short short8;
typedef __attribute__((ext_vector_type(4))) float f32x4;

__device__ __forceinline__ unsigned short f2b(float f){
    union { float f; uint32_t u; } v; v.f = f;
    uint32_t u = v.u;
    uint32_t r = u + 0x7fffu + ((u >> 16) & 1u);
    return (unsigned short)(r >> 16);
}

__device__ __forceinline__ void gload16(const unsigned short* g, unsigned short* l){
    __builtin_amdgcn_global_load_lds((const __attribute__((address_space(1))) void*)g,
                                     (__attribute__((address_space(3))) void*)l, 16, 0, 0);
}

// ---------------- prep: fp32 -> bf16 convert ----------------
__global__ void cvt_kernel(const float* __restrict__ in, unsigned short* __restrict__ out, int n4){
    int i = blockIdx.x*blockDim.x + threadIdx.x;
    if (i < n4){
        float4 v = ((const float4*)in)[i];
        ushort4 o;
        o.x = f2b(v.x); o.y = f2b(v.y); o.z = f2b(v.z); o.w = f2b(v.w);
        ((ushort4*)out)[i] = o;
    }
}

// ---------------- prep: materialize relative-position bias (H,197,197) ----------------
__global__ void bias_kernel(const int* __restrict__ rel_index, const float* __restrict__ rel_table,
                            float* __restrict__ biasm){
    int i = blockIdx.x*blockDim.x + threadIdx.x;
    if (i < NTOK*NTOK){
        int idx = rel_index[i];
        #pragma unroll
        for (int h = 0; h < NH; ++h)
            biasm[h*NTOK*NTOK + i] = rel_table[idx*NH + h];
    }
}

// ---------------- bf16 MFMA GEMM, 128x128 tile, BK=64, SINGLE-buffered (m97) ----------------
// 32KB LDS -> up to 5 blocks/CU: TLP hides staging latency (m114 lesson).
// T2 XOR chunk swizzle (both sides) + XCD-chunked A-panel-major dispatch.
// C[m][n] = sum_k A[m][k] * Bw[n][k]   (Bw is row-major (N,K) == B^T)
// EPI==0: scatter to Q/K/V with bias+scale fold.  EPI==1: fp32 out + proj_b.
template<int EPI>
__global__ __launch_bounds__(256) void gemm_kernel(
    const unsigned short* __restrict__ A,
    const unsigned short* __restrict__ Bw,
    float* __restrict__ Cout,
    unsigned short* __restrict__ Qo,
    unsigned short* __restrict__ Ko,
    unsigned short* __restrict__ Vo,
    const float* __restrict__ b0,
    const float* __restrict__ b2,
    int ny)
{
    __shared__ __align__(16) unsigned short As[128*64];
    __shared__ __align__(16) unsigned short Bs[128*64];
    const int tid  = threadIdx.x;
    const int lane = tid & 63;
    const int wave = tid >> 6;
    const int wr = wave >> 1, wc = wave & 1;
    const int lr = lane & 15;
    const int g  = lane >> 4;

    // ---- bijective XCD-chunked decode (m204): id -> w, y-fastest within chunk ----
    const int NB   = gridDim.x;
    const int base = NB >> 3;
    const int rem  = NB & 7;
    const int id   = blockIdx.x;
    const int xcd  = id & 7;
    const int qq   = id >> 3;
    const int start = (xcd < rem) ? xcd*(base+1) : rem*(base+1) + (xcd-rem)*base;
    const int w    = start + qq;
    const int bx   = w / ny;
    const int by   = w - bx*ny;
    const int m0 = bx * 128;
    const int n0 = by * 128;
    const int NT = CDIM / 64;   // 12 K-tiles

    f32x4 acc[4][4];
    #pragma unroll
    for (int i=0;i<4;i++)
        #pragma unroll
        for (int j=0;j<4;j++) acc[i][j] = (f32x4){0.f,0.f,0.f,0.f};

    // Precompute staging addresses: per thread, 4 chunks of A + 4 of B (16B each).
    // LDS layout linear [row][64]; global source chunk pre-swizzled: cg = c ^ (r&7).
    const unsigned short* gA[4];
    const unsigned short* gB[4];
    int lofs[4];
    #pragma unroll
    for (int j=0;j<4;j++){
        int a  = j*4096 + tid*16;       // byte offset within 16KB tile
        int r  = a >> 7;                // row (128B rows)
        int c  = (a >> 4) & 7;          // 16B chunk within row
        int cg = c ^ (r & 7);           // swizzled source chunk
        gA[j] = A  + (size_t)(m0 + r)*CDIM + cg*8;
        gB[j] = Bw + (size_t)(n0 + r)*CDIM + cg*8;
        lofs[j] = a >> 1;               // element offset in LDS
    }
    // Precompute ds_read swizzled k-offsets (row&7 == lr&7 for all frag rows)
    int koff0 = 8*((0*4 + g) ^ (lr & 7));
    int koff1 = 8*((1*4 + g) ^ (lr & 7));

    #pragma unroll 1
    for (int kt = 0; kt < NT; ++kt){
        __syncthreads();                 // all waves done reading previous tile
        #pragma unroll
        for (int j=0;j<4;j++){
            gload16(gA[j] + kt*64, &As[lofs[j]]);
            gload16(gB[j] + kt*64, &Bs[lofs[j]]);
        }
        __syncthreads();                 // includes vmcnt(0) drain
        #pragma unroll
        for (int kk=0; kk<2; ++kk){
            const int ko = kk ? koff1 : koff0;
            short8 af[4], bf[4];
            #pragma unroll
            for (int mt=0;mt<4;mt++)
                af[mt] = *(const short8*)&As[(wr*64+mt*16+lr)*64 + ko];
            #pragma unroll
            for (int nt=0;nt<4;nt++)
                bf[nt] = *(const short8*)&Bs[(wc*64+nt*16+lr)*64 + ko];
            #pragma unroll
            for (int mt=0;mt<4;mt++)
                #pragma unroll
                for (int nt=0;nt<4;nt++)
                    acc[mt][nt] = __builtin_amdgcn_mfma_f32_16x16x32_bf16(af[mt], bf[nt], acc[mt][nt], 0,0,0);
        }
    }

    #pragma unroll
    for (int mt=0;mt<4;mt++){
        #pragma unroll
        for (int r=0;r<4;r++){
            int m = m0 + wr*64 + mt*16 + g*4 + r;
            if (m >= MTOT) continue;
            if (EPI == 1){
                #pragma unroll
                for (int nt=0;nt<4;nt++){
                    int n = n0 + wc*64 + nt*16 + lr;
                    Cout[(size_t)m*CDIM + n] = acc[mt][nt][r] + b0[n];
                }
            } else {
                int bidx = m / NTOK;
                int tok  = m - bidx*NTOK;
                #pragma unroll
                for (int nt=0;nt<4;nt++){
                    int n = n0 + wc*64 + nt*16 + lr;
                    int which = n / CDIM;
                    int hn = n - which*CDIM;
                    int h = hn >> 6, d = hn & 63;
                    size_t off = ((size_t)((bidx*NH + h)*NTOK + tok))*HD + d;
                    float v = acc[mt][nt][r];
                    if (which == 0)      Qo[off] = f2b((v + b0[hn]) * SCALE);
                    else if (which == 1) Ko[off] = f2b(v);
                    else                 Vo[off] = f2b(v + b2[hn]);
                }
            }
        }
    }
}

// ---------------- fused attention: one block per (b,h) ----------------
__global__ __launch_bounds__(256) void attn_kernel(
    const unsigned short* __restrict__ Q,
    const unsigned short* __restrict__ K,
    const unsigned short* __restrict__ V,
    const float* __restrict__ biasm,
    unsigned short* __restrict__ Ao)
{
    __shared__ unsigned short Vt[64][232];      // V transposed, k-dim padded with zeros
    __shared__ unsigned short Ps[4][16][232];   // per-wave P strip, stride 232 to dodge bank conflicts
    const int bh = blockIdx.x;
    const int b = bh / NH;
    const int h = bh - b*NH;
    const unsigned short* Qh = Q + (size_t)bh*NTOK*HD;
    const unsigned short* Kh = K + (size_t)bh*NTOK*HD;
    const unsigned short* Vh = V + (size_t)bh*NTOK*HD;
    const float* bh_bias = biasm + (size_t)h*NTOK*NTOK;
    const int tid = threadIdx.x, lane = tid & 63, wave = tid >> 6;
    const int lr = lane & 15, g = lane >> 4, ko = g*8;

    // zero Vt (pad region must be 0)
    for (int i = tid; i < 64*232/2; i += 256) ((uint32_t*)Vt)[i] = 0;
    __syncthreads();
    // fill Vt transposed: Vt[d][t] = V[t][d]
    {
        int d0 = (tid & 7) * 8;
        for (int t = tid >> 3; t < NTOK; t += 32){
            short8 v = *(const short8*)&Vh[t*HD + d0];
            #pragma unroll
            for (int j=0;j<8;j++) Vt[d0+j][t] = (unsigned short)v[j];
        }
    }
    __syncthreads();

    for (int s = wave; s < 13; s += 4){
        int qrow = s*16 + lr; qrow = qrow > 196 ? 196 : qrow;
        short8 qa0 = *(const short8*)&Qh[qrow*HD + ko];
        short8 qa1 = *(const short8*)&Qh[qrow*HD + 32 + ko];
        f32x4 S[13];
        #pragma unroll
        for (int t=0;t<13;t++){
            int kc = t*16 + lr; kc = kc > 196 ? 196 : kc;
            short8 kb0 = *(const short8*)&Kh[kc*HD + ko];
            short8 kb1 = *(const short8*)&Kh[kc*HD + 32 + ko];
            f32x4 a = (f32x4){0.f,0.f,0.f,0.f};
            a = __builtin_amdgcn_mfma_f32_16x16x32_bf16(qa0, kb0, a, 0,0,0);
            a = __builtin_amdgcn_mfma_f32_16x16x32_bf16(qa1, kb1, a, 0,0,0);
            S[t] = a;
        }
        // bias + col mask + row max
        float rmax[4] = {-3e38f,-3e38f,-3e38f,-3e38f};
        #pragma unroll
        for (int t=0;t<13;t++){
            int col = t*16 + lr;
            bool cok = col < NTOK;
            int colc = cok ? col : 196;
            #pragma unroll
            for (int r=0;r<4;r++){
                int row = s*16 + g*4 + r; row = row > 196 ? 196 : row;
                float xv = S[t][r] + bh_bias[row*NTOK + colc];
                xv = cok ? xv : -1e30f;
                S[t][r] = xv;
                rmax[r] = fmaxf(rmax[r], xv);
            }
        }
        #pragma unroll
        for (int r=0;r<4;r++)
            #pragma unroll
            for (int msk=1; msk<16; msk<<=1)
                rmax[r] = fmaxf(rmax[r], __shfl_xor(rmax[r], msk));
        float rsum[4] = {0.f,0.f,0.f,0.f};
        #pragma unroll
        for (int t=0;t<13;t++)
            #pragma unroll
            for (int r=0;r<4;r++){
                float e = __expf(S[t][r] - rmax[r]);
                S[t][r] = e;
                rsum[r] += e;
            }
        #pragma unroll
        for (int r=0;r<4;r++){
            #pragma unroll
            for (int msk=1; msk<16; msk<<=1)
                rsum[r] += __shfl_xor(rsum[r], msk);
            rsum[r] = 1.f / rsum[r];
        }
        // write normalized P (bf16) to this wave's LDS strip; cols>=197 are exp(-1e30)=0, pad 208..223 zeroed
        #pragma unroll
        for (int t=0;t<13;t++)
            #pragma unroll
            for (int r=0;r<4;r++)
                Ps[wave][g*4+r][t*16+lr] = f2b(S[t][r] * rsum[r]);
        #pragma unroll
        for (int r=0;r<4;r++) Ps[wave][g*4+r][208+lr] = 0;
        asm volatile("s_waitcnt lgkmcnt(0)" ::: "memory");
        // P @ V
        f32x4 pv[4];
        #pragma unroll
        for (int nt=0;nt<4;nt++) pv[nt] = (f32x4){0.f,0.f,0.f,0.f};
        #pragma unroll
        for (int ks=0; ks<7; ks++){
            int k0 = ks*32 + ko;
            short8 pa = *(const short8*)&Ps[wave][lr][k0];
            #pragma unroll
            for (int nt=0;nt<4;nt++){
                short8 vb = *(const short8*)&Vt[nt*16+lr][k0];
                pv[nt] = __builtin_amdgcn_mfma_f32_16x16x32_bf16(pa, vb, pv[nt], 0,0,0);
            }
        }
        // store to (B*N, 768) bf16
        #pragma unroll
        for (int nt=0;nt<4;nt++)
            #pragma unroll
            for (int r=0;r<4;r++){
                int tok = s*16 + g*4 + r;
                if (tok < NTOK)
                    Ao[(size_t)(b*NTOK + tok)*CDIM + h*HD + nt*16 + lr] = f2b(pv[nt][r]);
            }
    }
}

extern "C" void kernel_launch(void* const* d_in, const int* in_sizes, int n_in,
                              void* d_out, int out_size, void* d_ws, size_t ws_size,
                              hipStream_t stream)
{
    const float* x        = (const float*)d_in[0];
    const float* qkv_w    = (const float*)d_in[1];
    const float* q_bias   = (const float*)d_in[2];
    const float* v_bias   = (const float*)d_in[3];
    const float* rel_tab  = (const float*)d_in[4];
    const float* proj_w   = (const float*)d_in[5];
    const float* proj_b   = (const float*)d_in[6];
    const int*   rel_idx  = (const int*)d_in[7];
    float* out = (float*)d_out;

    char* w = (char*)d_ws;
    unsigned short* xb    = (unsigned short*)w; w += (size_t)MPAD*CDIM*2;
    unsigned short* wqkv  = (unsigned short*)w; w += (size_t)3*CDIM*CDIM*2;
    unsigned short* wproj = (unsigned short*)w; w += (size_t)CDIM*CDIM*2;
    unsigned short* Qb    = (unsigned short*)w; w += (size_t)BB*NH*NTOK*HD*2;
    unsigned short* Kb    = (unsigned short*)w; w += (size_t)BB*NH*NTOK*HD*2;
    unsigned short* Vb    = (unsigned short*)w; w += (size_t)BB*NH*NTOK*HD*2;
    float*          biasm = (float*)w;          w += (size_t)NH*NTOK*NTOK*4;
    unsigned short* aob   = (unsigned short*)w; w += (size_t)MPAD*CDIM*2;

    int n1 = MTOT*CDIM/4;
    cvt_kernel<<<(n1+255)/256, 256, 0, stream>>>(x, xb, n1);
    int n2 = 3*CDIM*CDIM/4;
    cvt_kernel<<<(n2+255)/256, 256, 0, stream>>>(qkv_w, wqkv, n2);
    int n3 = CDIM*CDIM/4;
    cvt_kernel<<<(n3+255)/256, 256, 0, stream>>>(proj_w, wproj, n3);
    bias_kernel<<<(NTOK*NTOK+255)/256, 256, 0, stream>>>(rel_idx, rel_tab, biasm);

    gemm_kernel<0><<<99*18, 256, 0, stream>>>(xb, wqkv, nullptr, Qb, Kb, Vb, q_bias, v_bias, 18);
    attn_kernel<<<BB*NH, 256, 0, stream>>>(Qb, Kb, Vb, biasm, aob);
    gemm_kernel<1><<<99*6, 256, 0, stream>>>(aob, wproj, out, nullptr, nullptr, nullptr, proj_b, nullptr, 6);
}

// Round 5
// 210.637 us; speedup vs baseline: 1.0267x; 1.0267x over previous
//
#include <hip/hip_runtime.h>
#include <stdint.h>

#define NTOK 197
#define HD 64
#define NH 12
#define CDIM 768
#define BB 64
#define MTOT (BB*NTOK)      /* 12608 */
#define MPAD 12672          /* 99*128, proj A tiling */
#define XPAD 12800          /* 50*256, qkv A tiling */
#define SCALE 0.125f

typedef __attribute__((ext_vector_type(8))) short short8;
typedef __attribute__((ext_vector_type(4))) float f32x4;

__device__ __forceinline__ unsigned short f2b(float f){
    union { float f; uint32_t u; } v; v.f = f;
    uint32_t u = v.u;
    uint32_t r = u + 0x7fffu + ((u >> 16) & 1u);
    return (unsigned short)(r >> 16);
}

__device__ __forceinline__ void gload16(const unsigned short* g, unsigned short* l){
    __builtin_amdgcn_global_load_lds((const __attribute__((address_space(1))) void*)g,
                                     (__attribute__((address_space(3))) void*)l, 16, 0, 0);
}

// ---------------- prep: fp32 -> bf16 convert ----------------
__global__ void cvt_kernel(const float* __restrict__ in, unsigned short* __restrict__ out, int n4){
    int i = blockIdx.x*blockDim.x + threadIdx.x;
    if (i < n4){
        float4 v = ((const float4*)in)[i];
        ushort4 o;
        o.x = f2b(v.x); o.y = f2b(v.y); o.z = f2b(v.z); o.w = f2b(v.w);
        ((ushort4*)out)[i] = o;
    }
}

// ---------------- prep: materialize relative-position bias (H,197,197) ----------------
__global__ void bias_kernel(const int* __restrict__ rel_index, const float* __restrict__ rel_table,
                            float* __restrict__ biasm){
    int i = blockIdx.x*blockDim.x + threadIdx.x;
    if (i < NTOK*NTOK){
        int idx = rel_index[i];
        #pragma unroll
        for (int h = 0; h < NH; ++h)
            biasm[h*NTOK*NTOK + i] = rel_table[idx*NH + h];
    }
}

// ================= QKV GEMM: 256x256 tile, BK=64, 8 waves, dbuf + counted vmcnt =================
// T2 XOR chunk swizzle (both sides), T5 setprio, XCD panel-major decode.
// C[m][n] = sum_k A[m][k]*Bw[n][k]; scatter epilogue to Q/K/V with bias+scale fold.
__global__ __launch_bounds__(512,1) void qkv_gemm_kernel(
    const unsigned short* __restrict__ A,
    const unsigned short* __restrict__ Bw,
    unsigned short* __restrict__ Qo,
    unsigned short* __restrict__ Ko,
    unsigned short* __restrict__ Vo,
    const float* __restrict__ b0,
    const float* __restrict__ b2)
{
    __shared__ __align__(16) unsigned short As[2][256*64];
    __shared__ __align__(16) unsigned short Bs[2][256*64];
    const int tid  = threadIdx.x;
    const int lane = tid & 63;
    const int wave = tid >> 6;
    const int wrr = wave >> 2;          // 0..1  (M half)
    const int wcc = wave & 3;           // 0..3  (N quarter)
    const int lr = lane & 15;
    const int g  = lane >> 4;

    // bijective XCD-chunked decode, y-fastest (9 col-tiles share an A panel)
    const int NB   = gridDim.x;         // 450
    const int base = NB >> 3;
    const int rem  = NB & 7;
    const int id   = blockIdx.x;
    const int xcd  = id & 7;
    const int qq   = id >> 3;
    const int start = (xcd < rem) ? xcd*(base+1) : rem*(base+1) + (xcd-rem)*base;
    const int w    = start + qq;
    const int bx   = w / 9;
    const int by   = w - bx*9;
    const int m0 = bx * 256;
    const int n0 = by * 256;
    const int NT = CDIM / 64;           // 12 K-tiles

    f32x4 acc[8][4];
    #pragma unroll
    for (int i=0;i<8;i++)
        #pragma unroll
        for (int j=0;j<4;j++) acc[i][j] = (f32x4){0.f,0.f,0.f,0.f};

    // staging addresses: 4 chunks A + 4 chunks B per thread (16B each)
    const unsigned short* gA[4];
    const unsigned short* gB[4];
    int lofs[4];
    #pragma unroll
    for (int j=0;j<4;j++){
        int a  = j*8192 + tid*16;       // byte offset within 32KB tile
        int r  = a >> 7;                // row (128B rows), 0..255
        int c  = (a >> 4) & 7;          // 16B chunk within row
        int cg = c ^ (r & 7);           // swizzled source chunk
        gA[j] = A  + (size_t)(m0 + r)*CDIM + cg*8;
        gB[j] = Bw + (size_t)(n0 + r)*CDIM + cg*8;
        lofs[j] = a >> 1;
    }
    auto stage = [&](int buf, int kt){
        #pragma unroll
        for (int j=0;j<4;j++){
            gload16(gA[j] + kt*64, &As[buf][lofs[j]]);
            gload16(gB[j] + kt*64, &Bs[buf][lofs[j]]);
        }
    };
    // ds_read swizzled k-offsets (frag rows ≡ lr mod 8)
    const int koff0 = 8*((0*4 + g) ^ (lr & 7));
    const int koff1 = 8*((1*4 + g) ^ (lr & 7));

    stage(0, 0);
    stage(1, 1);
    asm volatile("s_waitcnt vmcnt(8)" ::: "memory");   // K-tile 0 landed
    __builtin_amdgcn_s_barrier();

    int cur = 0;
    #pragma unroll 1
    for (int t = 0; t < NT; ++t){
        #pragma unroll
        for (int kk=0; kk<2; ++kk){
            const int ko = kk ? koff1 : koff0;
            short8 af[8], bf[4];
            #pragma unroll
            for (int mt=0;mt<8;mt++)
                af[mt] = *(const short8*)&As[cur][(wrr*128+mt*16+lr)*64 + ko];
            #pragma unroll
            for (int nt=0;nt<4;nt++)
                bf[nt] = *(const short8*)&Bs[cur][(wcc*64+nt*16+lr)*64 + ko];
            __builtin_amdgcn_s_setprio(1);
            #pragma unroll
            for (int mt=0;mt<8;mt++)
                #pragma unroll
                for (int nt=0;nt<4;nt++)
                    acc[mt][nt] = __builtin_amdgcn_mfma_f32_16x16x32_bf16(af[mt], bf[nt], acc[mt][nt], 0,0,0);
            __builtin_amdgcn_s_setprio(0);
        }
        __builtin_amdgcn_s_barrier();       // all waves done reading buf[cur]
        if (t + 2 < NT){
            stage(cur, t + 2);
            asm volatile("s_waitcnt vmcnt(8)" ::: "memory");  // tile t+1 landed
        } else if (t + 1 < NT){
            asm volatile("s_waitcnt vmcnt(0)" ::: "memory");
        }
        if (t + 1 < NT){
            __builtin_amdgcn_s_barrier();
            cur ^= 1;
        }
    }

    #pragma unroll
    for (int mt=0;mt<8;mt++){
        #pragma unroll
        for (int r=0;r<4;r++){
            int m = m0 + wrr*128 + mt*16 + g*4 + r;
            if (m >= MTOT) continue;
            int bidx = m / NTOK;
            int tok  = m - bidx*NTOK;
            #pragma unroll
            for (int nt=0;nt<4;nt++){
                int n = n0 + wcc*64 + nt*16 + lr;
                int which = n / CDIM;
                int hn = n - which*CDIM;
                int h = hn >> 6, d = hn & 63;
                size_t off = ((size_t)((bidx*NH + h)*NTOK + tok))*HD + d;
                float v = acc[mt][nt][r];
                if (which == 0)      Qo[off] = f2b((v + b0[hn]) * SCALE);
                else if (which == 1) Ko[off] = f2b(v);
                else                 Vo[off] = f2b(v + b2[hn]);
            }
        }
    }
}

// ================= proj GEMM: 128x128 tile, BK=64, single-buffer (unchanged R4) =================
__global__ __launch_bounds__(256) void proj_gemm_kernel(
    const unsigned short* __restrict__ A,
    const unsigned short* __restrict__ Bw,
    float* __restrict__ Cout,
    const float* __restrict__ b0,
    int ny)
{
    __shared__ __align__(16) unsigned short As[128*64];
    __shared__ __align__(16) unsigned short Bs[128*64];
    const int tid  = threadIdx.x;
    const int lane = tid & 63;
    const int wave = tid >> 6;
    const int wr = wave >> 1, wc = wave & 1;
    const int lr = lane & 15;
    const int g  = lane >> 4;

    const int NB   = gridDim.x;
    const int base = NB >> 3;
    const int rem  = NB & 7;
    const int id   = blockIdx.x;
    const int xcd  = id & 7;
    const int qq   = id >> 3;
    const int start = (xcd < rem) ? xcd*(base+1) : rem*(base+1) + (xcd-rem)*base;
    const int w    = start + qq;
    const int bx   = w / ny;
    const int by   = w - bx*ny;
    const int m0 = bx * 128;
    const int n0 = by * 128;
    const int NT = CDIM / 64;

    f32x4 acc[4][4];
    #pragma unroll
    for (int i=0;i<4;i++)
        #pragma unroll
        for (int j=0;j<4;j++) acc[i][j] = (f32x4){0.f,0.f,0.f,0.f};

    const unsigned short* gA[4];
    const unsigned short* gB[4];
    int lofs[4];
    #pragma unroll
    for (int j=0;j<4;j++){
        int a  = j*4096 + tid*16;
        int r  = a >> 7;
        int c  = (a >> 4) & 7;
        int cg = c ^ (r & 7);
        gA[j] = A  + (size_t)(m0 + r)*CDIM + cg*8;
        gB[j] = Bw + (size_t)(n0 + r)*CDIM + cg*8;
        lofs[j] = a >> 1;
    }
    const int koff0 = 8*((0*4 + g) ^ (lr & 7));
    const int koff1 = 8*((1*4 + g) ^ (lr & 7));

    #pragma unroll 1
    for (int kt = 0; kt < NT; ++kt){
        __syncthreads();
        #pragma unroll
        for (int j=0;j<4;j++){
            gload16(gA[j] + kt*64, &As[lofs[j]]);
            gload16(gB[j] + kt*64, &Bs[lofs[j]]);
        }
        __syncthreads();
        #pragma unroll
        for (int kk=0; kk<2; ++kk){
            const int ko = kk ? koff1 : koff0;
            short8 af[4], bf[4];
            #pragma unroll
            for (int mt=0;mt<4;mt++)
                af[mt] = *(const short8*)&As[(wr*64+mt*16+lr)*64 + ko];
            #pragma unroll
            for (int nt=0;nt<4;nt++)
                bf[nt] = *(const short8*)&Bs[(wc*64+nt*16+lr)*64 + ko];
            #pragma unroll
            for (int mt=0;mt<4;mt++)
                #pragma unroll
                for (int nt=0;nt<4;nt++)
                    acc[mt][nt] = __builtin_amdgcn_mfma_f32_16x16x32_bf16(af[mt], bf[nt], acc[mt][nt], 0,0,0);
        }
    }

    #pragma unroll
    for (int mt=0;mt<4;mt++){
        #pragma unroll
        for (int r=0;r<4;r++){
            int m = m0 + wr*64 + mt*16 + g*4 + r;
            if (m >= MTOT) continue;
            #pragma unroll
            for (int nt=0;nt<4;nt++){
                int n = n0 + wc*64 + nt*16 + lr;
                Cout[(size_t)m*CDIM + n] = acc[mt][nt][r] + b0[n];
            }
        }
    }
}

// ---------------- fused attention: one block per (b,h) ----------------
__global__ __launch_bounds__(256) void attn_kernel(
    const unsigned short* __restrict__ Q,
    const unsigned short* __restrict__ K,
    const unsigned short* __restrict__ V,
    const float* __restrict__ biasm,
    unsigned short* __restrict__ Ao)
{
    __shared__ unsigned short Vt[64][232];
    __shared__ unsigned short Ps[4][16][232];
    const int bh = blockIdx.x;
    const int b = bh / NH;
    const int h = bh - b*NH;
    const unsigned short* Qh = Q + (size_t)bh*NTOK*HD;
    const unsigned short* Kh = K + (size_t)bh*NTOK*HD;
    const unsigned short* Vh = V + (size_t)bh*NTOK*HD;
    const float* bh_bias = biasm + (size_t)h*NTOK*NTOK;
    const int tid = threadIdx.x, lane = tid & 63, wave = tid >> 6;
    const int lr = lane & 15, g = lane >> 4, ko = g*8;

    for (int i = tid; i < 64*232/2; i += 256) ((uint32_t*)Vt)[i] = 0;
    __syncthreads();
    {
        int d0 = (tid & 7) * 8;
        for (int t = tid >> 3; t < NTOK; t += 32){
            short8 v = *(const short8*)&Vh[t*HD + d0];
            #pragma unroll
            for (int j=0;j<8;j++) Vt[d0+j][t] = (unsigned short)v[j];
        }
    }
    __syncthreads();

    for (int s = wave; s < 13; s += 4){
        int qrow = s*16 + lr; qrow = qrow > 196 ? 196 : qrow;
        short8 qa0 = *(const short8*)&Qh[qrow*HD + ko];
        short8 qa1 = *(const short8*)&Qh[qrow*HD + 32 + ko];
        f32x4 S[13];
        #pragma unroll
        for (int t=0;t<13;t++){
            int kc = t*16 + lr; kc = kc > 196 ? 196 : kc;
            short8 kb0 = *(const short8*)&Kh[kc*HD + ko];
            short8 kb1 = *(const short8*)&Kh[kc*HD + 32 + ko];
            f32x4 a = (f32x4){0.f,0.f,0.f,0.f};
            a = __builtin_amdgcn_mfma_f32_16x16x32_bf16(qa0, kb0, a, 0,0,0);
            a = __builtin_amdgcn_mfma_f32_16x16x32_bf16(qa1, kb1, a, 0,0,0);
            S[t] = a;
        }
        float rmax[4] = {-3e38f,-3e38f,-3e38f,-3e38f};
        #pragma unroll
        for (int t=0;t<13;t++){
            int col = t*16 + lr;
            bool cok = col < NTOK;
            int colc = cok ? col : 196;
            #pragma unroll
            for (int r=0;r<4;r++){
                int row = s*16 + g*4 + r; row = row > 196 ? 196 : row;
                float xv = S[t][r] + bh_bias[row*NTOK + colc];
                xv = cok ? xv : -1e30f;
                S[t][r] = xv;
                rmax[r] = fmaxf(rmax[r], xv);
            }
        }
        #pragma unroll
        for (int r=0;r<4;r++)
            #pragma unroll
            for (int msk=1; msk<16; msk<<=1)
                rmax[r] = fmaxf(rmax[r], __shfl_xor(rmax[r], msk));
        float rsum[4] = {0.f,0.f,0.f,0.f};
        #pragma unroll
        for (int t=0;t<13;t++)
            #pragma unroll
            for (int r=0;r<4;r++){
                float e = __expf(S[t][r] - rmax[r]);
                S[t][r] = e;
                rsum[r] += e;
            }
        #pragma unroll
        for (int r=0;r<4;r++){
            #pragma unroll
            for (int msk=1; msk<16; msk<<=1)
                rsum[r] += __shfl_xor(rsum[r], msk);
            rsum[r] = 1.f / rsum[r];
        }
        #pragma unroll
        for (int t=0;t<13;t++)
            #pragma unroll
            for (int r=0;r<4;r++)
                Ps[wave][g*4+r][t*16+lr] = f2b(S[t][r] * rsum[r]);
        #pragma unroll
        for (int r=0;r<4;r++) Ps[wave][g*4+r][208+lr] = 0;
        asm volatile("s_waitcnt lgkmcnt(0)" ::: "memory");
        f32x4 pv[4];
        #pragma unroll
        for (int nt=0;nt<4;nt++) pv[nt] = (f32x4){0.f,0.f,0.f,0.f};
        #pragma unroll
        for (int ks=0; ks<7; ks++){
            int k0 = ks*32 + ko;
            short8 pa = *(const short8*)&Ps[wave][lr][k0];
            #pragma unroll
            for (int nt=0;nt<4;nt++){
                short8 vb = *(const short8*)&Vt[nt*16+lr][k0];
                pv[nt] = __builtin_amdgcn_mfma_f32_16x16x32_bf16(pa, vb, pv[nt], 0,0,0);
            }
        }
        #pragma unroll
        for (int nt=0;nt<4;nt++)
            #pragma unroll
            for (int r=0;r<4;r++){
                int tok = s*16 + g*4 + r;
                if (tok < NTOK)
                    Ao[(size_t)(b*NTOK + tok)*CDIM + h*HD + nt*16 + lr] = f2b(pv[nt][r]);
            }
    }
}

extern "C" void kernel_launch(void* const* d_in, const int* in_sizes, int n_in,
                              void* d_out, int out_size, void* d_ws, size_t ws_size,
                              hipStream_t stream)
{
    const float* x        = (const float*)d_in[0];
    const float* qkv_w    = (const float*)d_in[1];
    const float* q_bias   = (const float*)d_in[2];
    const float* v_bias   = (const float*)d_in[3];
    const float* rel_tab  = (const float*)d_in[4];
    const float* proj_w   = (const float*)d_in[5];
    const float* proj_b   = (const float*)d_in[6];
    const int*   rel_idx  = (const int*)d_in[7];
    float* out = (float*)d_out;

    char* w = (char*)d_ws;
    unsigned short* xb    = (unsigned short*)w; w += (size_t)XPAD*CDIM*2;
    unsigned short* wqkv  = (unsigned short*)w; w += (size_t)3*CDIM*CDIM*2;
    unsigned short* wproj = (unsigned short*)w; w += (size_t)CDIM*CDIM*2;
    unsigned short* Qb    = (unsigned short*)w; w += (size_t)BB*NH*NTOK*HD*2;
    unsigned short* Kb    = (unsigned short*)w; w += (size_t)BB*NH*NTOK*HD*2;
    unsigned short* Vb    = (unsigned short*)w; w += (size_t)BB*NH*NTOK*HD*2;
    float*          biasm = (float*)w;          w += (size_t)NH*NTOK*NTOK*4;
    unsigned short* aob   = (unsigned short*)w; w += (size_t)MPAD*CDIM*2;

    int n1 = MTOT*CDIM/4;
    cvt_kernel<<<(n1+255)/256, 256, 0, stream>>>(x, xb, n1);
    int n2 = 3*CDIM*CDIM/4;
    cvt_kernel<<<(n2+255)/256, 256, 0, stream>>>(qkv_w, wqkv, n2);
    int n3 = CDIM*CDIM/4;
    cvt_kernel<<<(n3+255)/256, 256, 0, stream>>>(proj_w, wproj, n3);
    bias_kernel<<<(NTOK*NTOK+255)/256, 256, 0, stream>>>(rel_idx, rel_tab, biasm);

    qkv_gemm_kernel<<<50*9, 512, 0, stream>>>(xb, wqkv, Qb, Kb, Vb, q_bias, v_bias);
    attn_kernel<<<BB*NH, 256, 0, stream>>>(Qb, Kb, Vb, biasm, aob);
    proj_gemm_kernel<<<99*6, 256, 0, stream>>>(aob, wproj, out, proj_b, 6);
}

// Round 6
// 207.386 us; speedup vs baseline: 1.0428x; 1.0157x over previous
//
#include <hip/hip_runtime.h>
#include <stdint.h>

#define NTOK 197
#define HD 64
#define NH 12
#define CDIM 768
#define BB 64
#define MTOT (BB*NTOK)      /* 12608 */
#define XPAD 12800          /* 50*256 */
#define SCALE 0.125f

typedef __attribute__((ext_vector_type(8))) short short8;
typedef __attribute__((ext_vector_type(4))) float f32x4;
typedef unsigned short us;

#define VMW(n) asm volatile("s_waitcnt vmcnt(" #n ")" ::: "memory")

__device__ __forceinline__ us f2b(float f){
    union { float f; uint32_t u; } v; v.f = f;
    uint32_t u = v.u;
    uint32_t r = u + 0x7fffu + ((u >> 16) & 1u);
    return (us)(r >> 16);
}

__device__ __forceinline__ void gload16(const us* g, us* l){
    __builtin_amdgcn_global_load_lds((const __attribute__((address_space(1))) void*)g,
                                     (__attribute__((address_space(3))) void*)l, 16, 0, 0);
}

// ---------------- prep ----------------
__global__ void cvt_kernel(const float* __restrict__ in, us* __restrict__ out, int n4){
    int i = blockIdx.x*blockDim.x + threadIdx.x;
    if (i < n4){
        float4 v = ((const float4*)in)[i];
        ushort4 o;
        o.x = f2b(v.x); o.y = f2b(v.y); o.z = f2b(v.z); o.w = f2b(v.w);
        ((ushort4*)out)[i] = o;
    }
}

__global__ void bias_kernel(const int* __restrict__ rel_index, const float* __restrict__ rel_table,
                            float* __restrict__ biasm){
    int i = blockIdx.x*blockDim.x + threadIdx.x;
    if (i < NTOK*NTOK){
        int idx = rel_index[i];
        #pragma unroll
        for (int h = 0; h < NH; ++h)
            biasm[h*NTOK*NTOK + i] = rel_table[idx*NH + h];
    }
}

// ============ 8-wave pipelined GEMM: BM=256, BK=32, 4 LDS buffers, counted vmcnt ============
// Phase-interleaved: per K-tile {vmcnt(N); s_barrier; [dsB+dsA-lo | stageA(t+3)] MFMA x16;
// [dsA-hi | stageB(t+3)] MFMA x16}. Loads fly 3 K-tiles ahead; vmcnt never 0 until tail.
// Chunk swizzle c^=(row>>1)&3 pre-applied on global source, applied on ds_read (2-way = free).
// EPI==0: scatter Q/K/V epilogue (BN=256). EPI==1: fp32 + bias (BN=128).
template<int BN, int EPI>
__global__ __launch_bounds__(512,1) void gemm8_kernel(
    const us* __restrict__ A, const us* __restrict__ Bw,
    float* __restrict__ Cout, us* __restrict__ Qo, us* __restrict__ Ko, us* __restrict__ Vo,
    const float* __restrict__ b0, const float* __restrict__ b2, int ny)
{
    constexpr int NFR = BN/64;        // B frags per wave: 4 (qkv) / 2 (proj)
    constexpr int LB  = BN/128;       // B stage loads/thread: 2 / 1
    constexpr int ASZ = 256*32;       // A buffer elements
    constexpr int BSZ = BN*32;
    constexpr int BUF = ASZ + BSZ;
    constexpr int NT  = CDIM/32;      // 24 K-tiles
    constexpr int WBAND = BN/4;       // N cols per wave
    __shared__ us lds[4*BUF];

    const int tid  = threadIdx.x;
    const int lane = tid & 63;
    const int wave = tid >> 6;
    const int wrr = wave >> 2;        // 0..1 M half
    const int wcc = wave & 3;         // 0..3 N band
    const int lr = lane & 15;
    const int g  = lane >> 4;

    // bijective XCD-chunked decode, y-fastest (col-tiles share A panel)
    const int NB   = gridDim.x;
    const int base = NB >> 3;
    const int rem  = NB & 7;
    const int id   = blockIdx.x;
    const int xcd  = id & 7;
    const int qq   = id >> 3;
    const int start = (xcd < rem) ? xcd*(base+1) : rem*(base+1) + (xcd-rem)*base;
    const int w    = start + qq;
    const int bx   = w / ny;
    const int by   = w - bx*ny;
    const int m0 = bx * 256;
    const int n0 = by * BN;

    f32x4 acc[8][NFR];
    #pragma unroll
    for (int i=0;i<8;i++)
        #pragma unroll
        for (int j=0;j<NFR;j++) acc[i][j] = (f32x4){0.f,0.f,0.f,0.f};

    // staging source pointers (chunk pre-swizzled)
    const int ssw = (tid>>3)&3;
    const int cch = (tid&3) ^ ssw;
    const int ra  = tid>>2;                 // 0..127
    const us* gA0 = A  + (size_t)(m0 + ra)*CDIM + cch*8;
    const us* gA1 = gA0 + (size_t)128*CDIM;
    const us* gB0 = Bw + (size_t)(n0 + ra)*CDIM + cch*8;
    const us* gB1 = gB0 + (size_t)128*CDIM;

    auto stageA = [&](int kt, int bi){
        gload16(gA0 + kt*32, &lds[bi*BUF + tid*8]);
        gload16(gA1 + kt*32, &lds[bi*BUF + 4096 + tid*8]);
    };
    auto stageB = [&](int kt, int bi){
        gload16(gB0 + kt*32, &lds[bi*BUF + ASZ + tid*8]);
        if constexpr (LB == 2)
            gload16(gB1 + kt*32, &lds[bi*BUF + ASZ + 4096 + tid*8]);
    };

    // prologue: stage tiles 0..3 into buffers 0..3
    #pragma unroll
    for (int p=0;p<4;p++){ stageA(p,p); stageB(p,p); }

    // ds_read swizzled chunk offset: lane reads storage chunk g^((lr>>1)&3) -> true k-chunk g
    const int co = ((g ^ ((lr>>1)&3)))*8;

    #pragma unroll 1
    for (int t = 0; t < NT; ++t){
        const int bi = t & 3;
        if constexpr (LB == 2){
            if (t==0) VMW(12); else if (t<=NT-3) VMW(8); else if (t==NT-2) VMW(4); else VMW(0);
        } else {
            if (t==0) VMW(9);  else if (t<=NT-3) VMW(6); else if (t==NT-2) VMW(3); else VMW(0);
        }
        asm volatile("s_barrier" ::: "memory");
        const us* la = &lds[bi*BUF];
        const us* lb = la + ASZ;
        const bool st = (t >= 1) && (t <= NT-4);

        short8 bf[NFR];
        #pragma unroll
        for (int nt=0;nt<NFR;nt++)
            bf[nt] = *(const short8*)&lb[(wcc*WBAND + nt*16 + lr)*32 + co];
        short8 af[4];
        #pragma unroll
        for (int mt=0;mt<4;mt++)
            af[mt] = *(const short8*)&la[(wrr*128 + mt*16 + lr)*32 + co];
        if (st) stageA(t+3, (t+3)&3);
        __builtin_amdgcn_s_setprio(1);
        #pragma unroll
        for (int mt=0;mt<4;mt++)
            #pragma unroll
            for (int nt=0;nt<NFR;nt++)
                acc[mt][nt] = __builtin_amdgcn_mfma_f32_16x16x32_bf16(af[mt], bf[nt], acc[mt][nt], 0,0,0);
        __builtin_amdgcn_s_setprio(0);

        short8 ag[4];
        #pragma unroll
        for (int mt=0;mt<4;mt++)
            ag[mt] = *(const short8*)&la[(wrr*128 + (4+mt)*16 + lr)*32 + co];
        if (st) stageB(t+3, (t+3)&3);
        __builtin_amdgcn_s_setprio(1);
        #pragma unroll
        for (int mt=0;mt<4;mt++)
            #pragma unroll
            for (int nt=0;nt<NFR;nt++)
                acc[4+mt][nt] = __builtin_amdgcn_mfma_f32_16x16x32_bf16(ag[mt], bf[nt], acc[4+mt][nt], 0,0,0);
        __builtin_amdgcn_s_setprio(0);
    }

    #pragma unroll
    for (int mt=0;mt<8;mt++){
        #pragma unroll
        for (int r=0;r<4;r++){
            int m = m0 + wrr*128 + mt*16 + g*4 + r;
            if (m >= MTOT) continue;
            if (EPI == 1){
                #pragma unroll
                for (int nt=0;nt<NFR;nt++){
                    int n = n0 + wcc*WBAND + nt*16 + lr;
                    Cout[(size_t)m*CDIM + n] = acc[mt][nt][r] + b0[n];
                }
            } else {
                int bidx = m / NTOK;
                int tok  = m - bidx*NTOK;
                #pragma unroll
                for (int nt=0;nt<NFR;nt++){
                    int n = n0 + wcc*WBAND + nt*16 + lr;
                    int which = n / CDIM;
                    int hn = n - which*CDIM;
                    int h = hn >> 6, d = hn & 63;
                    size_t off = ((size_t)((bidx*NH + h)*NTOK + tok))*HD + d;
                    float v = acc[mt][nt][r];
                    if (which == 0)      Qo[off] = f2b((v + b0[hn]) * SCALE);
                    else if (which == 1) Ko[off] = f2b(v);
                    else                 Vo[off] = f2b(v + b2[hn]);
                }
            }
        }
    }
}

// ---------------- fused attention: one block per (b,h) ----------------
__global__ __launch_bounds__(256) void attn_kernel(
    const us* __restrict__ Q,
    const us* __restrict__ K,
    const us* __restrict__ V,
    const float* __restrict__ biasm,
    us* __restrict__ Ao)
{
    __shared__ us Vt[64][232];
    __shared__ us Ps[4][16][232];
    const int bh = blockIdx.x;
    const int b = bh / NH;
    const int h = bh - b*NH;
    const us* Qh = Q + (size_t)bh*NTOK*HD;
    const us* Kh = K + (size_t)bh*NTOK*HD;
    const us* Vh = V + (size_t)bh*NTOK*HD;
    const float* bh_bias = biasm + (size_t)h*NTOK*NTOK;
    const int tid = threadIdx.x, lane = tid & 63, wave = tid >> 6;
    const int lr = lane & 15, g = lane >> 4, ko = g*8;

    for (int i = tid; i < 64*232/2; i += 256) ((uint32_t*)Vt)[i] = 0;
    __syncthreads();
    {
        int d0 = (tid & 7) * 8;
        for (int t = tid >> 3; t < NTOK; t += 32){
            short8 v = *(const short8*)&Vh[t*HD + d0];
            #pragma unroll
            for (int j=0;j<8;j++) Vt[d0+j][t] = (us)v[j];
        }
    }
    __syncthreads();

    for (int s = wave; s < 13; s += 4){
        int qrow = s*16 + lr; qrow = qrow > 196 ? 196 : qrow;
        short8 qa0 = *(const short8*)&Qh[qrow*HD + ko];
        short8 qa1 = *(const short8*)&Qh[qrow*HD + 32 + ko];
        f32x4 S[13];
        #pragma unroll
        for (int t=0;t<13;t++){
            int kc = t*16 + lr; kc = kc > 196 ? 196 : kc;
            short8 kb0 = *(const short8*)&Kh[kc*HD + ko];
            short8 kb1 = *(const short8*)&Kh[kc*HD + 32 + ko];
            f32x4 a = (f32x4){0.f,0.f,0.f,0.f};
            a = __builtin_amdgcn_mfma_f32_16x16x32_bf16(qa0, kb0, a, 0,0,0);
            a = __builtin_amdgcn_mfma_f32_16x16x32_bf16(qa1, kb1, a, 0,0,0);
            S[t] = a;
        }
        float rmax[4] = {-3e38f,-3e38f,-3e38f,-3e38f};
        #pragma unroll
        for (int t=0;t<13;t++){
            int col = t*16 + lr;
            bool cok = col < NTOK;
            int colc = cok ? col : 196;
            #pragma unroll
            for (int r=0;r<4;r++){
                int row = s*16 + g*4 + r; row = row > 196 ? 196 : row;
                float xv = S[t][r] + bh_bias[row*NTOK + colc];
                xv = cok ? xv : -1e30f;
                S[t][r] = xv;
                rmax[r] = fmaxf(rmax[r], xv);
            }
        }
        #pragma unroll
        for (int r=0;r<4;r++)
            #pragma unroll
            for (int msk=1; msk<16; msk<<=1)
                rmax[r] = fmaxf(rmax[r], __shfl_xor(rmax[r], msk));
        float rsum[4] = {0.f,0.f,0.f,0.f};
        #pragma unroll
        for (int t=0;t<13;t++)
            #pragma unroll
            for (int r=0;r<4;r++){
                float e = __expf(S[t][r] - rmax[r]);
                S[t][r] = e;
                rsum[r] += e;
            }
        #pragma unroll
        for (int r=0;r<4;r++){
            #pragma unroll
            for (int msk=1; msk<16; msk<<=1)
                rsum[r] += __shfl_xor(rsum[r], msk);
            rsum[r] = 1.f / rsum[r];
        }
        #pragma unroll
        for (int t=0;t<13;t++)
            #pragma unroll
            for (int r=0;r<4;r++)
                Ps[wave][g*4+r][t*16+lr] = f2b(S[t][r] * rsum[r]);
        #pragma unroll
        for (int r=0;r<4;r++) Ps[wave][g*4+r][208+lr] = 0;
        asm volatile("s_waitcnt lgkmcnt(0)" ::: "memory");
        f32x4 pv[4];
        #pragma unroll
        for (int nt=0;nt<4;nt++) pv[nt] = (f32x4){0.f,0.f,0.f,0.f};
        #pragma unroll
        for (int ks=0; ks<7; ks++){
            int k0 = ks*32 + ko;
            short8 pa = *(const short8*)&Ps[wave][lr][k0];
            #pragma unroll
            for (int nt=0;nt<4;nt++){
                short8 vb = *(const short8*)&Vt[nt*16+lr][k0];
                pv[nt] = __builtin_amdgcn_mfma_f32_16x16x32_bf16(pa, vb, pv[nt], 0,0,0);
            }
        }
        #pragma unroll
        for (int nt=0;nt<4;nt++)
            #pragma unroll
            for (int r=0;r<4;r++){
                int tok = s*16 + g*4 + r;
                if (tok < NTOK)
                    Ao[(size_t)(b*NTOK + tok)*CDIM + h*HD + nt*16 + lr] = f2b(pv[nt][r]);
            }
    }
}

extern "C" void kernel_launch(void* const* d_in, const int* in_sizes, int n_in,
                              void* d_out, int out_size, void* d_ws, size_t ws_size,
                              hipStream_t stream)
{
    const float* x        = (const float*)d_in[0];
    const float* qkv_w    = (const float*)d_in[1];
    const float* q_bias   = (const float*)d_in[2];
    const float* v_bias   = (const float*)d_in[3];
    const float* rel_tab  = (const float*)d_in[4];
    const float* proj_w   = (const float*)d_in[5];
    const float* proj_b   = (const float*)d_in[6];
    const int*   rel_idx  = (const int*)d_in[7];
    float* out = (float*)d_out;

    char* w = (char*)d_ws;
    us* xb    = (us*)w; w += (size_t)XPAD*CDIM*2;
    us* wqkv  = (us*)w; w += (size_t)3*CDIM*CDIM*2;
    us* wproj = (us*)w; w += (size_t)CDIM*CDIM*2;
    us* Qb    = (us*)w; w += (size_t)BB*NH*NTOK*HD*2;
    us* Kb    = (us*)w; w += (size_t)BB*NH*NTOK*HD*2;
    us* Vb    = (us*)w; w += (size_t)BB*NH*NTOK*HD*2;
    float* biasm = (float*)w; w += (size_t)NH*NTOK*NTOK*4;
    us* aob   = (us*)w; w += (size_t)XPAD*CDIM*2;

    int n1 = MTOT*CDIM/4;
    cvt_kernel<<<(n1+255)/256, 256, 0, stream>>>(x, xb, n1);
    int n2 = 3*CDIM*CDIM/4;
    cvt_kernel<<<(n2+255)/256, 256, 0, stream>>>(qkv_w, wqkv, n2);
    int n3 = CDIM*CDIM/4;
    cvt_kernel<<<(n3+255)/256, 256, 0, stream>>>(proj_w, wproj, n3);
    bias_kernel<<<(NTOK*NTOK+255)/256, 256, 0, stream>>>(rel_idx, rel_tab, biasm);

    gemm8_kernel<256,0><<<50*9, 512, 0, stream>>>(xb, wqkv, nullptr, Qb, Kb, Vb, q_bias, v_bias, 9);
    attn_kernel<<<BB*NH, 256, 0, stream>>>(Qb, Kb, Vb, biasm, aob);
    gemm8_kernel<128,1><<<50*6, 512, 0, stream>>>(aob, wproj, out, nullptr, nullptr, nullptr, proj_b, nullptr, 6);
}